// Round 16
// baseline (99.482 us; speedup 1.0000x reference)
//
#include <hip/hip_runtime.h>
#include <hip/hip_bf16.h>
#include <stdint.h>

using bf16 = __bf16;
using bf16x4 = __attribute__((ext_vector_type(4))) __bf16;
using bf16x8 = __attribute__((ext_vector_type(8))) __bf16;
using f32x4 = __attribute__((ext_vector_type(4))) float;
using f32x16 = __attribute__((ext_vector_type(16))) float;
using u32x2 = __attribute__((ext_vector_type(2))) unsigned int;

static constexpr int SEQ = 2048;
static constexpr int NDIM = 1024;
static constexpr int NHEAD = 16;
static constexpr int HD = 64;
// fold softmax scale and log2(e) into Q so scores are already in log2 domain
static constexpr float QSCALE = 0.125f * 1.4426950408889634f;

__device__ __forceinline__ void load_lds16(const void* g, void* l) {
  __builtin_amdgcn_global_load_lds(
      (const __attribute__((address_space(1))) void*)g,
      (__attribute__((address_space(3))) void*)l, 16, 0, 0);
}

// pack two fp32 -> one u32 of two bf16 (lo = a, hi = b)
__device__ __forceinline__ uint32_t pk2(float a, float b) {
  uint16_t ua = __builtin_bit_cast(uint16_t, (bf16)a);
  uint16_t ub = __builtin_bit_cast(uint16_t, (bf16)b);
  return (uint32_t)ua | ((uint32_t)ub << 16);
}

// ---- fused prep: x fp32->bf16 (blocks 0..4095) + 4 weight transposes ------
// (r12 win: was 5 dispatches; fusing removed 4 launch gaps/tails, ~12 us)
__global__ __launch_bounds__(256) void k_prep(const float* __restrict__ x,
                                              const float* __restrict__ Wq,
                                              const float* __restrict__ Wk,
                                              const float* __restrict__ Wv,
                                              const float* __restrict__ Wp,
                                              bf16* __restrict__ x_bf,
                                              bf16* __restrict__ wqkvT,
                                              bf16* __restrict__ wpT) {
  __shared__ float t[32][33];
  int bid = blockIdx.x;
  if (bid < 4096) {  // cvt: 4096 blocks x 256 thr x 4 elems = 4096*1024
    int i = (bid * 256 + threadIdx.x) * 4;
    float4 v = *(const float4*)(x + i);
    bf16x4 o;
    o[0] = (bf16)v.x; o[1] = (bf16)v.y; o[2] = (bf16)v.z; o[3] = (bf16)v.w;
    *(bf16x4*)(x_bf + i) = o;
    return;
  }
  const float* W; bf16* WT; int N; int idx;
  if (bid < 5120)      { W = Wq; WT = wqkvT;                         N = 1024; idx = bid - 4096; }
  else if (bid < 5184) { W = Wk; WT = wqkvT + (size_t)1024 * 1024;   N = 64;   idx = bid - 5120; }
  else if (bid < 5248) { W = Wv; WT = wqkvT + (size_t)1088 * 1024;   N = 64;   idx = bid - 5184; }
  else                 { W = Wp; WT = wpT;                           N = 1024; idx = bid - 5248; }
  const int nb = N / 32;
  const int n0 = (idx % nb) * 32, k0 = (idx / nb) * 32;
  const int tx = threadIdx.x & 31, ty = threadIdx.x >> 5;  // 32 x 8
#pragma unroll
  for (int i = 0; i < 4; i++)
    t[ty + 8 * i][tx] = W[(size_t)(k0 + ty + 8 * i) * N + n0 + tx];
  __syncthreads();
#pragma unroll
  for (int i = 0; i < 4; i++)
    WT[(size_t)(n0 + ty + 8 * i) * 1024 + k0 + tx] = (bf16)t[tx][ty + 8 * i];
}

// ---------------- bf16 GEMM: C = A(MxK) @ BT(NxK)^T ----------------
// MODE 2: C fp32 + bias                           (output projection)
// MODE 3: fused QKV: col<1024 -> Q bf16 * scale; col in [1024,1088) -> K bf16
//         (C2); col >= 1088 -> V bf16 stored transposed per batch (C3)
// 128x64 tile (r11 win) + 2-phase LDS dbuf (r14, ~neutral; kept).
template <int BM, int BN, int WM, int WN, int MODE>
__global__ __launch_bounds__(256) void k_gemm(const bf16* __restrict__ A,
                                              const bf16* __restrict__ BT,
                                              void* __restrict__ C,
                                              void* __restrict__ C2,
                                              void* __restrict__ C3,
                                              const float* __restrict__ bias,
                                              int M, int N, int K, float scale) {
  __shared__ __align__(16) char As[2][BM * 128];
  __shared__ __align__(16) char Bs[2][BN * 128];
  const int lane = threadIdx.x & 63;
  const int wv = threadIdx.x >> 6;
  constexpr int NWC = BN / WN;
  const int wr = wv / NWC, wc = wv % NWC;
  const int g = lane >> 4, l15 = lane & 15;
  const int m0 = blockIdx.y * BM, n0 = blockIdx.x * BN;
  constexpr int MI = WM / 16, NI = WN / 16;

  f32x4 acc[MI][NI] = {};

  const int srow = lane >> 3;   // staging row within 8-row chunk
  const int c16 = lane & 7;     // staging 16B-column within row

  auto stage = [&](char* Ad, char* Bd, int kt) {
#pragma unroll
    for (int j = wv; j < BM / 8; j += 4) {
      int row = j * 8 + srow;
      const char* src = (const char*)A + (size_t)(m0 + row) * (K * 2) + kt * 2 +
                        ((c16 ^ (row & 7)) << 4);
      load_lds16(src, Ad + j * 1024);
    }
#pragma unroll
    for (int j = wv; j < BN / 8; j += 4) {
      int row = j * 8 + srow;
      const char* src = (const char*)BT + (size_t)(n0 + row) * (K * 2) + kt * 2 +
                        ((c16 ^ (row & 7)) << 4);
      load_lds16(src, Bd + j * 1024);
    }
  };

  auto compute = [&](const char* Ab, const char* Bb) {
#pragma unroll
    for (int kk = 0; kk < 2; kk++) {
      bf16x8 af[MI], bfr[NI];
#pragma unroll
      for (int mi = 0; mi < MI; mi++) {
        int row = wr * WM + mi * 16 + l15;
        af[mi] = *(const bf16x8*)(Ab + row * 128 + (((kk * 4 + g) ^ (row & 7)) << 4));
      }
#pragma unroll
      for (int ni = 0; ni < NI; ni++) {
        int row = wc * WN + ni * 16 + l15;
        bfr[ni] = *(const bf16x8*)(Bb + row * 128 + (((kk * 4 + g) ^ (row & 7)) << 4));
      }
#pragma unroll
      for (int mi = 0; mi < MI; mi++)
#pragma unroll
        for (int ni = 0; ni < NI; ni++)
          acc[mi][ni] = __builtin_amdgcn_mfma_f32_16x16x32_bf16(af[mi], bfr[ni],
                                                                acc[mi][ni], 0, 0, 0);
    }
  };

  stage(As[0], Bs[0], 0);
  __syncthreads();
  for (int kt = 0; kt < K; kt += 128) {
    stage(As[1], Bs[1], kt + 64);           // always valid: kt+64 < K
    compute(As[0], Bs[0]);
    __syncthreads();
    if (kt + 128 < K) stage(As[0], Bs[0], kt + 128);
    compute(As[1], Bs[1]);
    __syncthreads();
  }

#pragma unroll
  for (int mi = 0; mi < MI; mi++)
#pragma unroll
    for (int ni = 0; ni < NI; ni++) {
      int col = n0 + wc * WN + ni * 16 + l15;
      int rowb = m0 + wr * WM + mi * 16 + g * 4;
      if (MODE == 2) {
        float bv = bias[col];
#pragma unroll
        for (int r = 0; r < 4; r++)
          ((float*)C)[(size_t)(rowb + r) * N + col] = acc[mi][ni][r] + bv;
      } else {  // MODE 3: fused QKV epilogue
        if (col < 1024) {
#pragma unroll
          for (int r = 0; r < 4; r++)
            ((bf16*)C)[(size_t)(rowb + r) * 1024 + col] =
                (bf16)(acc[mi][ni][r] * scale);
        } else if (col < 1088) {
#pragma unroll
          for (int r = 0; r < 4; r++)
            ((bf16*)C2)[(size_t)(rowb + r) * 64 + (col - 1024)] =
                (bf16)acc[mi][ni][r];
        } else {
#pragma unroll
          for (int r = 0; r < 4; r++) {
            int m = rowb + r;
            ((bf16*)C3)[((size_t)((m >> 11) * 64 + (col - 1088))) * 2048 +
                        (m & 2047)] = (bf16)acc[mi][ni][r];
          }
        }
      }
    }
}

// ---- fused attention: 8-wave blocks, shared LDS K/V tiles, 2-phase dbuf ----
// grid = B * H * (SEQ/128) = 512 blocks; block = 8 waves = 4 qsub x 2 kvhalf.
// r16: cross-kvb software pipeline WITH a small live set (why r12 spilled:
// it kept kf0+kf1+s0+s1 = 144 regs; here s0 dies into p0 BEFORE kvb1's QK
// reuses the single kf buffer -> peak ~124 < 128). Order per tile:
//   QK(0) -> exp2(0) -> QK(1) -> pack(0)+PV(0) -> exp2(1) -> pack(1)+PV(1)
// so pack(0) VALU + PV(0)'s 10 MFMAs cover QK(1)'s ds_read/MFMA latency,
// and exp2(1) finds s1 ready. r15's accsum (row sums on matrix pipe) kept.
// REGISTER BUDGET (r4/r5/r7/r12): (512,4) = 128-cap unified pool.
// Tripwire = WRITE_SIZE >> 9 MB means spill: revert.
__global__ __launch_bounds__(512, 4) void k_attn(const bf16* __restrict__ Q,
                                                 const bf16* __restrict__ K,
                                                 const bf16* __restrict__ VT,
                                                 bf16* __restrict__ O) {
  __shared__ __align__(16) char smem[65536];
  int bid = blockIdx.x;
  int q128 = bid & 15;
  int h = (bid >> 4) & 15;
  int b = bid >> 8;
  int wv = threadIdx.x >> 6, lane = threadIdx.x & 63;
  int l31 = lane & 31, hi = lane >> 5;
  int qs = wv & 3, kh = wv >> 2;
  int q0 = q128 * 128 + qs * 32;

  const bf16* qrow =
      Q + ((size_t)(b * SEQ + q0 + l31) * NDIM + h * HD + hi * 8);
  bf16x8 aq[4];
#pragma unroll
  for (int f = 0; f < 4; f++) aq[f] = *(const bf16x8*)(qrow + f * 16);

  const int srow = lane >> 3, c16 = lane & 7;
  const int kvbeg = kh * (SEQ / 2);

  auto stage = [&](int bb, int t) {
    char* base = smem + bb * 32768 + kh * 16384;
    const int kv0 = kvbeg + t * 64;
#pragma unroll
    for (int j = 0; j < 4; j++) {
      int c = qs * 4 + j;
      if (c < 8) {
        const char* src = (const char*)K +
                          (size_t)(b * SEQ + kv0 + c * 8 + srow) * 128 +
                          ((c16 ^ srow) << 4);
        load_lds16(src, base + c * 1024);
      } else {
        const char* src = (const char*)VT +
                          (size_t)(b * 64 + (c - 8) * 8 + srow) * (SEQ * 2) +
                          (size_t)kv0 * 2 + ((c16 ^ srow) << 4);
        load_lds16(src, base + c * 1024);
      }
    }
  };

  f32x16 acc[2] = {};   // [dc]; lane: O[q=(r&3)+8(r>>2)+4hi][d=dc*32+l31]
  f32x16 accsum = {};   // row sums via mfma(pa, ones): same r-indexing as acc

  bf16x8 vones;
#pragma unroll
  for (int i = 0; i < 8; i++) vones[i] = (bf16)1.0f;

  // build one PV A-frag from 8 consecutive p values (bf16 pack + lane swap)
  auto mkfrag = [&](const float* p) {
    uint32_t t0 = pk2(p[0], p[1]);
    uint32_t t1 = pk2(p[2], p[3]);
    uint32_t t2 = pk2(p[4], p[5]);
    uint32_t t3 = pk2(p[6], p[7]);
    u32x2 rA = __builtin_amdgcn_permlane32_swap(t0, t2, false, false);
    u32x2 rB = __builtin_amdgcn_permlane32_swap(t1, t3, false, false);
    union { uint32_t u[4]; bf16x8 v; } af;
    af.u[0] = rA[0]; af.u[1] = rB[0]; af.u[2] = rA[1]; af.u[3] = rB[1];
    return af.v;
  };

  // pack + PV + accsum for one 32-kv sub-tile (kvb = 0 or 1)
  auto pvstep = [&](const float* p, char* Vl, int kvb) {
#pragma unroll
    for (int n = 0; n < 2; n++) {
      bf16x8 pa = mkfrag(p + 8 * n);
      __builtin_amdgcn_s_setprio(1);
#pragma unroll
      for (int dc = 0; dc < 2; dc++) {
        bf16x8 vf = *(const bf16x8*)(Vl + (dc * 32 + l31) * 128 +
                                     (((kvb * 4 + n * 2 + hi) ^ (l31 & 7))
                                      << 4));
        acc[dc] = __builtin_amdgcn_mfma_f32_32x32x16_bf16(pa, vf, acc[dc],
                                                          0, 0, 0);
      }
      accsum = __builtin_amdgcn_mfma_f32_32x32x16_bf16(pa, vones, accsum,
                                                       0, 0, 0);
      __builtin_amdgcn_s_setprio(0);
    }
  };

  // compute one staged 64-kv tile, cross-kvb pipelined
  auto compute = [&](char* Kl, char* Vl) {
    bf16x8 kf[4];
    // QK for kvb=0
#pragma unroll
    for (int f = 0; f < 4; f++)
      kf[f] = *(const bf16x8*)(Kl + l31 * 128 +
                               (((f * 2 + hi) ^ (l31 & 7)) << 4));
    f32x16 s0 = {};
    __builtin_amdgcn_s_setprio(1);
#pragma unroll
    for (int f = 0; f < 4; f++)
      s0 = __builtin_amdgcn_mfma_f32_32x32x16_bf16(kf[f], aq[f], s0, 0, 0, 0);
    __builtin_amdgcn_s_setprio(0);
    // s0 dies into p0 NOW, freeing regs for s1
    float p0[16];
#pragma unroll
    for (int i = 0; i < 16; i++) p0[i] = __builtin_amdgcn_exp2f(s0[i]);
    // QK for kvb=1 (independent; its latency is covered by pack(0)+PV(0))
#pragma unroll
    for (int f = 0; f < 4; f++)
      kf[f] = *(const bf16x8*)(Kl + (32 + l31) * 128 +
                               (((f * 2 + hi) ^ (l31 & 7)) << 4));
    f32x16 s1 = {};
    __builtin_amdgcn_s_setprio(1);
#pragma unroll
    for (int f = 0; f < 4; f++)
      s1 = __builtin_amdgcn_mfma_f32_32x32x16_bf16(kf[f], aq[f], s1, 0, 0, 0);
    __builtin_amdgcn_s_setprio(0);
    // pack + PV for kvb=0 while s1's MFMAs complete
    pvstep(p0, Vl, 0);
    // exp2 + pack + PV for kvb=1
    float p1[16];
#pragma unroll
    for (int i = 0; i < 16; i++) p1[i] = __builtin_amdgcn_exp2f(s1[i]);
    pvstep(p1, Vl, 1);
  };

  char* K0 = smem + kh * 16384;
  char* V0 = K0 + 8192;
  char* K1 = smem + 32768 + kh * 16384;
  char* V1 = K1 + 8192;

  stage(0, 0);
  __syncthreads();

#pragma unroll 1
  for (int t = 0; t < 16; t += 2) {
    stage(1, t + 1);            // always valid: t+1 <= 15
    compute(K0, V0);
    __syncthreads();
    if (t + 2 < 16) stage(0, t + 2);
    compute(K1, V1);
    __syncthreads();
  }

  // merge the two kv-halves: kh=1 writes partials, kh=0 adds + outputs.
  // [4 qs][64 lanes][49 f32] = 50176 B <= 64 KB; stride 49 is conflict-free.
  float* mb = (float*)smem;
  if (kh == 1) {
    float* dst = mb + ((size_t)(qs * 64 + lane)) * 49;
#pragma unroll
    for (int dc = 0; dc < 2; dc++)
#pragma unroll
      for (int r = 0; r < 16; r++) dst[dc * 16 + r] = acc[dc][r];
#pragma unroll
    for (int r = 0; r < 16; r++) dst[32 + r] = accsum[r];
  }
  __syncthreads();
  if (kh == 0) {
    const float* src = mb + ((size_t)(qs * 64 + lane)) * 49;
#pragma unroll
    for (int dc = 0; dc < 2; dc++)
#pragma unroll
      for (int r = 0; r < 16; r++) acc[dc][r] += src[dc * 16 + r];
#pragma unroll
    for (int r = 0; r < 16; r++) accsum[r] += src[32 + r];
#pragma unroll
    for (int r = 0; r < 16; r++) {
      int q_r = (r & 3) + 8 * (r >> 2) + 4 * hi;
      float rinv = 1.0f / accsum[r];
#pragma unroll
      for (int dc = 0; dc < 2; dc++)
        O[(size_t)(b * SEQ + q0 + q_r) * NDIM + h * HD + dc * 32 + l31] =
            (bf16)(acc[dc][r] * rinv);
    }
  }
}

extern "C" void kernel_launch(void* const* d_in, const int* in_sizes, int n_in,
                              void* d_out, int out_size, void* d_ws, size_t ws_size,
                              hipStream_t stream) {
  const float* x = (const float*)d_in[0];
  const float* Wq = (const float*)d_in[1];
  const float* Wk = (const float*)d_in[2];
  const float* Wv = (const float*)d_in[3];
  const float* Wp = (const float*)d_in[4];
  const float* bp = (const float*)d_in[5];
  float* out = (float*)d_out;

  size_t off = 0;
  char* wsb = (char*)d_ws;
  auto alloc = [&](size_t bytes) {
    char* p = wsb + off;
    off += bytes;
    return p;
  };
  bf16* x_bf = (bf16*)alloc((size_t)4096 * 1024 * 2);
  bf16* wqkvT = (bf16*)alloc((size_t)1152 * 1024 * 2);  // [WqT;WkT;WvT]
  bf16* wpT = (bf16*)alloc((size_t)1024 * 1024 * 2);
  bf16* Qb = (bf16*)alloc((size_t)4096 * 1024 * 2);
  bf16* Kb = (bf16*)alloc((size_t)4096 * 64 * 2);
  bf16* VTb = (bf16*)alloc((size_t)2 * 64 * 2048 * 2);
  bf16* AOb = (bf16*)alloc((size_t)4096 * 1024 * 2);

  // fused prep: cvt (4096 blocks) + Wq (1024) + Wk (64) + Wv (64) + Wp (1024)
  k_prep<<<6272, 256, 0, stream>>>(x, Wq, Wk, Wv, Wp, x_bf, wqkvT, wpT);

  // fused Q/K/V projection: N = 1152 = 1024(Q) + 64(K) + 64(V)
  k_gemm<128, 64, 64, 32, 3><<<dim3(18, 32), 256, 0, stream>>>(
      x_bf, wqkvT, Qb, Kb, VTb, nullptr, 4096, 1152, 1024, QSCALE);

  k_attn<<<512, 512, 0, stream>>>(Qb, Kb, VTb, AOb);

  // output projection + bias, fp32 out
  k_gemm<128, 64, 64, 32, 2><<<dim3(16, 32), 256, 0, stream>>>(
      AOb, wpT, out, nullptr, nullptr, bp, 4096, 1024, 1024, 1.0f);
}

// Round 17
// 95.130 us; speedup vs baseline: 1.0458x; 1.0458x over previous
//
#include <hip/hip_runtime.h>
#include <hip/hip_bf16.h>
#include <stdint.h>

using bf16 = __bf16;
using bf16x4 = __attribute__((ext_vector_type(4))) __bf16;
using bf16x8 = __attribute__((ext_vector_type(8))) __bf16;
using f32x4 = __attribute__((ext_vector_type(4))) float;
using f32x16 = __attribute__((ext_vector_type(16))) float;
using u32x2 = __attribute__((ext_vector_type(2))) unsigned int;

static constexpr int SEQ = 2048;
static constexpr int NDIM = 1024;
static constexpr int NHEAD = 16;
static constexpr int HD = 64;
// fold softmax scale and log2(e) into Q so scores are already in log2 domain
static constexpr float QSCALE = 0.125f * 1.4426950408889634f;

__device__ __forceinline__ void load_lds16(const void* g, void* l) {
  __builtin_amdgcn_global_load_lds(
      (const __attribute__((address_space(1))) void*)g,
      (__attribute__((address_space(3))) void*)l, 16, 0, 0);
}

// pack two fp32 -> one u32 of two bf16 (lo = a, hi = b)
__device__ __forceinline__ uint32_t pk2(float a, float b) {
  uint16_t ua = __builtin_bit_cast(uint16_t, (bf16)a);
  uint16_t ub = __builtin_bit_cast(uint16_t, (bf16)b);
  return (uint32_t)ua | ((uint32_t)ub << 16);
}

// ---- fused prep: x fp32->bf16 (blocks 0..4095) + 4 weight transposes ------
// (r12 win: was 5 dispatches; fusing removed 4 launch gaps/tails, ~12 us)
__global__ __launch_bounds__(256) void k_prep(const float* __restrict__ x,
                                              const float* __restrict__ Wq,
                                              const float* __restrict__ Wk,
                                              const float* __restrict__ Wv,
                                              const float* __restrict__ Wp,
                                              bf16* __restrict__ x_bf,
                                              bf16* __restrict__ wqkvT,
                                              bf16* __restrict__ wpT) {
  __shared__ float t[32][33];
  int bid = blockIdx.x;
  if (bid < 4096) {  // cvt: 4096 blocks x 256 thr x 4 elems = 4096*1024
    int i = (bid * 256 + threadIdx.x) * 4;
    float4 v = *(const float4*)(x + i);
    bf16x4 o;
    o[0] = (bf16)v.x; o[1] = (bf16)v.y; o[2] = (bf16)v.z; o[3] = (bf16)v.w;
    *(bf16x4*)(x_bf + i) = o;
    return;
  }
  const float* W; bf16* WT; int N; int idx;
  if (bid < 5120)      { W = Wq; WT = wqkvT;                         N = 1024; idx = bid - 4096; }
  else if (bid < 5184) { W = Wk; WT = wqkvT + (size_t)1024 * 1024;   N = 64;   idx = bid - 5120; }
  else if (bid < 5248) { W = Wv; WT = wqkvT + (size_t)1088 * 1024;   N = 64;   idx = bid - 5184; }
  else                 { W = Wp; WT = wpT;                           N = 1024; idx = bid - 5248; }
  const int nb = N / 32;
  const int n0 = (idx % nb) * 32, k0 = (idx / nb) * 32;
  const int tx = threadIdx.x & 31, ty = threadIdx.x >> 5;  // 32 x 8
#pragma unroll
  for (int i = 0; i < 4; i++)
    t[ty + 8 * i][tx] = W[(size_t)(k0 + ty + 8 * i) * N + n0 + tx];
  __syncthreads();
#pragma unroll
  for (int i = 0; i < 4; i++)
    WT[(size_t)(n0 + ty + 8 * i) * 1024 + k0 + tx] = (bf16)t[tx][ty + 8 * i];
}

// ---------------- bf16 GEMM: C = A(MxK) @ BT(NxK)^T ----------------
// MODE 2: C fp32 + bias                           (output projection)
// MODE 3: fused QKV: col<1024 -> Q bf16 * scale; col in [1024,1088) -> K bf16
//         (C2); col >= 1088 -> V bf16 stored transposed per batch (C3)
// 128x64 tile (r11 win) + 2-phase LDS dbuf (r14, ~neutral; kept).
template <int BM, int BN, int WM, int WN, int MODE>
__global__ __launch_bounds__(256) void k_gemm(const bf16* __restrict__ A,
                                              const bf16* __restrict__ BT,
                                              void* __restrict__ C,
                                              void* __restrict__ C2,
                                              void* __restrict__ C3,
                                              const float* __restrict__ bias,
                                              int M, int N, int K, float scale) {
  __shared__ __align__(16) char As[2][BM * 128];
  __shared__ __align__(16) char Bs[2][BN * 128];
  const int lane = threadIdx.x & 63;
  const int wv = threadIdx.x >> 6;
  constexpr int NWC = BN / WN;
  const int wr = wv / NWC, wc = wv % NWC;
  const int g = lane >> 4, l15 = lane & 15;
  const int m0 = blockIdx.y * BM, n0 = blockIdx.x * BN;
  constexpr int MI = WM / 16, NI = WN / 16;

  f32x4 acc[MI][NI] = {};

  const int srow = lane >> 3;   // staging row within 8-row chunk
  const int c16 = lane & 7;     // staging 16B-column within row

  auto stage = [&](char* Ad, char* Bd, int kt) {
#pragma unroll
    for (int j = wv; j < BM / 8; j += 4) {
      int row = j * 8 + srow;
      const char* src = (const char*)A + (size_t)(m0 + row) * (K * 2) + kt * 2 +
                        ((c16 ^ (row & 7)) << 4);
      load_lds16(src, Ad + j * 1024);
    }
#pragma unroll
    for (int j = wv; j < BN / 8; j += 4) {
      int row = j * 8 + srow;
      const char* src = (const char*)BT + (size_t)(n0 + row) * (K * 2) + kt * 2 +
                        ((c16 ^ (row & 7)) << 4);
      load_lds16(src, Bd + j * 1024);
    }
  };

  auto compute = [&](const char* Ab, const char* Bb) {
#pragma unroll
    for (int kk = 0; kk < 2; kk++) {
      bf16x8 af[MI], bfr[NI];
#pragma unroll
      for (int mi = 0; mi < MI; mi++) {
        int row = wr * WM + mi * 16 + l15;
        af[mi] = *(const bf16x8*)(Ab + row * 128 + (((kk * 4 + g) ^ (row & 7)) << 4));
      }
#pragma unroll
      for (int ni = 0; ni < NI; ni++) {
        int row = wc * WN + ni * 16 + l15;
        bfr[ni] = *(const bf16x8*)(Bb + row * 128 + (((kk * 4 + g) ^ (row & 7)) << 4));
      }
#pragma unroll
      for (int mi = 0; mi < MI; mi++)
#pragma unroll
        for (int ni = 0; ni < NI; ni++)
          acc[mi][ni] = __builtin_amdgcn_mfma_f32_16x16x32_bf16(af[mi], bfr[ni],
                                                                acc[mi][ni], 0, 0, 0);
    }
  };

  stage(As[0], Bs[0], 0);
  __syncthreads();
  for (int kt = 0; kt < K; kt += 128) {
    stage(As[1], Bs[1], kt + 64);           // always valid: kt+64 < K
    compute(As[0], Bs[0]);
    __syncthreads();
    if (kt + 128 < K) stage(As[0], Bs[0], kt + 128);
    compute(As[1], Bs[1]);
    __syncthreads();
  }

#pragma unroll
  for (int mi = 0; mi < MI; mi++)
#pragma unroll
    for (int ni = 0; ni < NI; ni++) {
      int col = n0 + wc * WN + ni * 16 + l15;
      int rowb = m0 + wr * WM + mi * 16 + g * 4;
      if (MODE == 2) {
        float bv = bias[col];
#pragma unroll
        for (int r = 0; r < 4; r++)
          ((float*)C)[(size_t)(rowb + r) * N + col] = acc[mi][ni][r] + bv;
      } else {  // MODE 3: fused QKV epilogue
        if (col < 1024) {
#pragma unroll
          for (int r = 0; r < 4; r++)
            ((bf16*)C)[(size_t)(rowb + r) * 1024 + col] =
                (bf16)(acc[mi][ni][r] * scale);
        } else if (col < 1088) {
#pragma unroll
          for (int r = 0; r < 4; r++)
            ((bf16*)C2)[(size_t)(rowb + r) * 64 + (col - 1024)] =
                (bf16)acc[mi][ni][r];
        } else {
#pragma unroll
          for (int r = 0; r < 4; r++) {
            int m = rowb + r;
            ((bf16*)C3)[((size_t)((m >> 11) * 64 + (col - 1088))) * 2048 +
                        (m & 2047)] = (bf16)acc[mi][ni][r];
          }
        }
      }
    }
}

// ---- fused attention: 8-wave blocks, shared LDS K/V tiles, 2-phase dbuf ----
// grid = B * H * (SEQ/128) = 512 blocks; block = 8 waves = 4 qsub x 2 kvhalf.
// r17: REVERT to r15 (measured best: 50.6 us, no spill). r16's cross-kvb
// pipeline spilled: p0[16] live across QK(1) pushed peak to ~130 > 128-cap
// (WRITE 9.2->18.4 MB, 58 us). CONCLUSION (3rd confirmation: r7/r12/r16): at
// 4 waves/SIMD under the 128-reg bucket this kernel has NO register headroom
// for cross-phase pipelining; compiler-sequential + 4-deep wave interleave is
// the optimum for this structure.
// r15's accsum: row sums on the matrix pipe (mfma(pa, ones)) -- kills the
// exp2->lsum VALU serialization + epilogue shfls. Swapped QK (mfma(K,Q)):
// softmax lane-local; pk2+permlane32_swap builds PV A-frags in-register.
// REGISTER BUDGET (r4/r5/r7/r12/r16): (512,4) = 128-cap unified pool.
// Tripwire = WRITE_SIZE >> 9 MB means spill: revert.
__global__ __launch_bounds__(512, 4) void k_attn(const bf16* __restrict__ Q,
                                                 const bf16* __restrict__ K,
                                                 const bf16* __restrict__ VT,
                                                 bf16* __restrict__ O) {
  __shared__ __align__(16) char smem[65536];
  int bid = blockIdx.x;
  int q128 = bid & 15;
  int h = (bid >> 4) & 15;
  int b = bid >> 8;
  int wv = threadIdx.x >> 6, lane = threadIdx.x & 63;
  int l31 = lane & 31, hi = lane >> 5;
  int qs = wv & 3, kh = wv >> 2;
  int q0 = q128 * 128 + qs * 32;

  const bf16* qrow =
      Q + ((size_t)(b * SEQ + q0 + l31) * NDIM + h * HD + hi * 8);
  bf16x8 aq[4];
#pragma unroll
  for (int f = 0; f < 4; f++) aq[f] = *(const bf16x8*)(qrow + f * 16);

  const int srow = lane >> 3, c16 = lane & 7;
  const int kvbeg = kh * (SEQ / 2);

  auto stage = [&](int bb, int t) {
    char* base = smem + bb * 32768 + kh * 16384;
    const int kv0 = kvbeg + t * 64;
#pragma unroll
    for (int j = 0; j < 4; j++) {
      int c = qs * 4 + j;
      if (c < 8) {
        const char* src = (const char*)K +
                          (size_t)(b * SEQ + kv0 + c * 8 + srow) * 128 +
                          ((c16 ^ srow) << 4);
        load_lds16(src, base + c * 1024);
      } else {
        const char* src = (const char*)VT +
                          (size_t)(b * 64 + (c - 8) * 8 + srow) * (SEQ * 2) +
                          (size_t)kv0 * 2 + ((c16 ^ srow) << 4);
        load_lds16(src, base + c * 1024);
      }
    }
  };

  f32x16 acc[2] = {};   // [dc]; lane: O[q=(r&3)+8(r>>2)+4hi][d=dc*32+l31]
  f32x16 accsum = {};   // row sums via mfma(pa, ones): same r-indexing as acc

  bf16x8 vones;
#pragma unroll
  for (int i = 0; i < 8; i++) vones[i] = (bf16)1.0f;

  // compute one staged 64-kv tile at a STATIC buffer base
  auto compute = [&](char* Kl, char* Vl) {
#pragma unroll
    for (int kvb = 0; kvb < 2; kvb++) {
      bf16x8 kf[4];
#pragma unroll
      for (int f = 0; f < 4; f++)
        kf[f] = *(const bf16x8*)(Kl + (kvb * 32 + l31) * 128 +
                                 (((f * 2 + hi) ^ (l31 & 7)) << 4));
      f32x16 s = {};
      __builtin_amdgcn_s_setprio(1);
#pragma unroll
      for (int f = 0; f < 4; f++)
        s = __builtin_amdgcn_mfma_f32_32x32x16_bf16(kf[f], aq[f], s, 0, 0, 0);
      __builtin_amdgcn_s_setprio(0);
      float p[16];
#pragma unroll
      for (int i = 0; i < 16; i++) p[i] = __builtin_amdgcn_exp2f(s[i]);
#pragma unroll
      for (int n = 0; n < 2; n++) {
        uint32_t t0 = pk2(p[8 * n + 0], p[8 * n + 1]);
        uint32_t t1 = pk2(p[8 * n + 2], p[8 * n + 3]);
        uint32_t t2 = pk2(p[8 * n + 4], p[8 * n + 5]);
        uint32_t t3 = pk2(p[8 * n + 6], p[8 * n + 7]);
        u32x2 rA = __builtin_amdgcn_permlane32_swap(t0, t2, false, false);
        u32x2 rB = __builtin_amdgcn_permlane32_swap(t1, t3, false, false);
        union { uint32_t u[4]; bf16x8 v; } af;
        af.u[0] = rA[0]; af.u[1] = rB[0]; af.u[2] = rA[1]; af.u[3] = rB[1];
        __builtin_amdgcn_s_setprio(1);
#pragma unroll
        for (int dc = 0; dc < 2; dc++) {
          bf16x8 vf = *(const bf16x8*)(Vl + (dc * 32 + l31) * 128 +
                                       (((kvb * 4 + n * 2 + hi) ^ (l31 & 7))
                                        << 4));
          acc[dc] = __builtin_amdgcn_mfma_f32_32x32x16_bf16(af.v, vf, acc[dc],
                                                            0, 0, 0);
        }
        accsum = __builtin_amdgcn_mfma_f32_32x32x16_bf16(af.v, vones, accsum,
                                                         0, 0, 0);
        __builtin_amdgcn_s_setprio(0);
      }
    }
  };

  char* K0 = smem + kh * 16384;
  char* V0 = K0 + 8192;
  char* K1 = smem + 32768 + kh * 16384;
  char* V1 = K1 + 8192;

  stage(0, 0);
  __syncthreads();

#pragma unroll 1
  for (int t = 0; t < 16; t += 2) {
    stage(1, t + 1);            // always valid: t+1 <= 15
    compute(K0, V0);
    __syncthreads();
    if (t + 2 < 16) stage(0, t + 2);
    compute(K1, V1);
    __syncthreads();
  }

  // merge the two kv-halves: kh=1 writes partials, kh=0 adds + outputs.
  // [4 qs][64 lanes][49 f32] = 50176 B <= 64 KB; stride 49 is conflict-free.
  float* mb = (float*)smem;
  if (kh == 1) {
    float* dst = mb + ((size_t)(qs * 64 + lane)) * 49;
#pragma unroll
    for (int dc = 0; dc < 2; dc++)
#pragma unroll
      for (int r = 0; r < 16; r++) dst[dc * 16 + r] = acc[dc][r];
#pragma unroll
    for (int r = 0; r < 16; r++) dst[32 + r] = accsum[r];
  }
  __syncthreads();
  if (kh == 0) {
    const float* src = mb + ((size_t)(qs * 64 + lane)) * 49;
#pragma unroll
    for (int dc = 0; dc < 2; dc++)
#pragma unroll
      for (int r = 0; r < 16; r++) acc[dc][r] += src[dc * 16 + r];
#pragma unroll
    for (int r = 0; r < 16; r++) accsum[r] += src[32 + r];
#pragma unroll
    for (int r = 0; r < 16; r++) {
      int q_r = (r & 3) + 8 * (r >> 2) + 4 * hi;
      float rinv = 1.0f / accsum[r];
#pragma unroll
      for (int dc = 0; dc < 2; dc++)
        O[(size_t)(b * SEQ + q0 + q_r) * NDIM + h * HD + dc * 32 + l31] =
            (bf16)(acc[dc][r] * rinv);
    }
  }
}

extern "C" void kernel_launch(void* const* d_in, const int* in_sizes, int n_in,
                              void* d_out, int out_size, void* d_ws, size_t ws_size,
                              hipStream_t stream) {
  const float* x = (const float*)d_in[0];
  const float* Wq = (const float*)d_in[1];
  const float* Wk = (const float*)d_in[2];
  const float* Wv = (const float*)d_in[3];
  const float* Wp = (const float*)d_in[4];
  const float* bp = (const float*)d_in[5];
  float* out = (float*)d_out;

  size_t off = 0;
  char* wsb = (char*)d_ws;
  auto alloc = [&](size_t bytes) {
    char* p = wsb + off;
    off += bytes;
    return p;
  };
  bf16* x_bf = (bf16*)alloc((size_t)4096 * 1024 * 2);
  bf16* wqkvT = (bf16*)alloc((size_t)1152 * 1024 * 2);  // [WqT;WkT;WvT]
  bf16* wpT = (bf16*)alloc((size_t)1024 * 1024 * 2);
  bf16* Qb = (bf16*)alloc((size_t)4096 * 1024 * 2);
  bf16* Kb = (bf16*)alloc((size_t)4096 * 64 * 2);
  bf16* VTb = (bf16*)alloc((size_t)2 * 64 * 2048 * 2);
  bf16* AOb = (bf16*)alloc((size_t)4096 * 1024 * 2);

  // fused prep: cvt (4096 blocks) + Wq (1024) + Wk (64) + Wv (64) + Wp (1024)
  k_prep<<<6272, 256, 0, stream>>>(x, Wq, Wk, Wv, Wp, x_bf, wqkvT, wpT);

  // fused Q/K/V projection: N = 1152 = 1024(Q) + 64(K) + 64(V)
  k_gemm<128, 64, 64, 32, 3><<<dim3(18, 32), 256, 0, stream>>>(
      x_bf, wqkvT, Qb, Kb, VTb, nullptr, 4096, 1152, 1024, QSCALE);

  k_attn<<<512, 512, 0, stream>>>(Qb, Kb, VTb, AOb);

  // output projection + bias, fp32 out
  k_gemm<128, 64, 64, 32, 2><<<dim3(16, 32), 256, 0, stream>>>(
      AOb, wpT, out, nullptr, nullptr, bp, 4096, 1024, 1024, 1.0f);
}